// Round 14
// baseline (138.709 us; speedup 1.0000x reference)
//
#include <hip/hip_runtime.h>
#include <hip/hip_bf16.h>

#define R_RES 384
#define S_SEQ 128
#define CM 256
#define CC 32
#define CZ 128

typedef __attribute__((ext_vector_type(8))) short bf16x8;
typedef __attribute__((ext_vector_type(4))) float f32x4;
typedef __attribute__((ext_vector_type(4))) int i32x4;

__device__ __forceinline__ short tobf16(float f) {
    union { __hip_bfloat16 h; short s; } u;
    u.h = __float2bfloat16(f);
    return u.s;
}

__device__ __forceinline__ void lgkm_barrier() {
    asm volatile("s_waitcnt lgkmcnt(0)" ::: "memory");
    __builtin_amdgcn_s_barrier();
    __builtin_amdgcn_sched_barrier(0);
}

// ---------------- kernel 0a: w_out (1024,128) f32 -> wbTf 16x16x32-B-frag tiled bf16 ------
__global__ void k_transpose_wout(const float* __restrict__ w_out, short* __restrict__ wbTf) {
    __shared__ float t[64][65];
    int k0 = blockIdx.x * 64;
    int z0 = blockIdx.y * 64;
    int tid = threadIdx.x;
    int c = tid & 63, rg = tid >> 6;
#pragma unroll
    for (int rr = 0; rr < 16; ++rr) {
        int kk = rg * 16 + rr;
        t[kk][c] = w_out[(size_t)(k0 + kk) * CZ + z0 + c];
    }
    __syncthreads();
#pragma unroll
    for (int l = 0; l < 2; ++l) {
        int id = l * 256 + tid;
        int f = id >> 6;
        int z16l = f >> 1, k32l = f & 1;
        int ln = id & 63;
        int zl = z16l * 16 + (ln & 15);
        int kl = k32l * 32 + (ln >> 4) * 8;
        bf16x8 pk;
#pragma unroll
        for (int j = 0; j < 8; ++j) pk[j] = tobf16(t[kl + j][zl]);
        int z16 = blockIdx.y * 4 + z16l;
        int k32 = blockIdx.x * 2 + k32l;
        *(bf16x8*)(wbTf + ((size_t)(z16 * 32 + k32) * 64 + ln) * 8) = pk;
    }
}

// ---------------- kernel 0b: pack w1|w2 (256,32) -> wcT (64,256) bf16 ----------------
__global__ void k_pack_w12(const float* __restrict__ w1, const float* __restrict__ w2,
                           short* __restrict__ wcT) {
    int idx = blockIdx.x * 256 + threadIdx.x;
    int k = idx >> 6, n = idx & 63;
    float v = (n < 32) ? w1[k * CC + n] : w2[k * CC + (n - 32)];
    wcT[n * CM + k] = tobf16(v);
}

// ---------------- kernel 1: LayerNorm + projections -> aTf, bTf fragment-tiled bf16 --------
__global__ __launch_bounds__(256) void k_ln_proj(
    const float* __restrict__ M, const float* __restrict__ ln_g, const float* __restrict__ ln_b,
    const float* __restrict__ b1, const float* __restrict__ b2,
    const short* __restrict__ wcT, short* __restrict__ aTf, short* __restrict__ bTf) {
    __shared__ short mnb[64 * 256];
    __shared__ short ab_s[2][32 * 72];
    int r = blockIdx.x >> 1;
    int s0 = (blockIdx.x & 1) * 64;
    int tid = threadIdx.x, lane = tid & 63, w = tid >> 6;
    int g = lane >> 4, r16 = lane & 15;
    float4 gv = *(const float4*)(ln_g + lane * 4);
    float4 bv = *(const float4*)(ln_b + lane * 4);
    for (int it = 0; it < 16; ++it) {
        int sl = it * 4 + w;
        float4 v = *(const float4*)(M + ((size_t)(s0 + sl) * R_RES + r) * CM + lane * 4);
        float sum = v.x + v.y + v.z + v.w;
        float sq = v.x * v.x + v.y * v.y + v.z * v.z + v.w * v.w;
#pragma unroll
        for (int off = 32; off; off >>= 1) {
            sum += __shfl_xor(sum, off);
            sq  += __shfl_xor(sq, off);
        }
        float mu = sum * (1.0f / 256.0f);
        float var = sq * (1.0f / 256.0f) - mu * mu;
        float rstd = rsqrtf(var + 1e-5f);
        short4 mnp;
        mnp.x = tobf16((v.x - mu) * rstd * gv.x + bv.x);
        mnp.y = tobf16((v.y - mu) * rstd * gv.y + bv.y);
        mnp.z = tobf16((v.z - mu) * rstd * gv.z + bv.z);
        mnp.w = tobf16((v.w - mu) * rstd * gv.w + bv.w);
        int byte = sl * 512 + lane * 8;
        byte ^= ((sl & 7) << 4);
        *(short4*)((char*)mnb + byte) = mnp;
    }
    __syncthreads();
    f32x4 acc[4] = {{0,0,0,0},{0,0,0,0},{0,0,0,0},{0,0,0,0}};
    int srow = w * 16 + r16;
#pragma unroll
    for (int ks = 0; ks < 8; ++ks) {
        int byte = srow * 512 + ks * 64 + g * 16;
        byte ^= ((srow & 7) << 4);
        bf16x8 af = *(const bf16x8*)((const char*)mnb + byte);
#pragma unroll
        for (int nt = 0; nt < 4; ++nt) {
            bf16x8 bf = *(const bf16x8*)(wcT + (nt * 16 + r16) * CM + ks * 32 + g * 8);
            acc[nt] = __builtin_amdgcn_mfma_f32_16x16x32_bf16(af, bf, acc[nt], 0, 0, 0);
        }
    }
#pragma unroll
    for (int nt = 0; nt < 4; ++nt) {
        int n = nt * 16 + r16;
        int x = n & 31, sel = n >> 5;
        float bias = sel ? b2[x] : b1[x];
#pragma unroll
        for (int rr = 0; rr < 4; ++rr) {
            int sl = w * 16 + g * 4 + rr;
            ab_s[sel][x * 72 + sl] = tobf16(acc[nt][rr] + bias);
        }
    }
    __syncthreads();
    int piece = tid >> 6;
    int fl = piece >> 1, kl = piece & 1;
    int ln = tid & 63;
    int x = fl * 16 + (ln & 15);
    int s_loc = kl * 32 + (ln >> 4) * 8;
    i32x4 va = *(const i32x4*)((const char*)ab_s[0] + (x * 72 + s_loc) * 2);
    i32x4 vb = *(const i32x4*)((const char*)ab_s[1] + (x * 72 + s_loc) * 2);
    size_t off = ((((size_t)r * 2 + fl) * 4 + (s0 >> 5) + kl) * 64 + ln) * 16;
    *(i32x4*)((char*)aTf + off) = va;
    *(i32x4*)((char*)bTf + off) = vb;
}

// ---------------- kernel 2: persistent cross-tile-pipelined fused kernel (v2) ----------------
// 256 blocks x 512 thr, 36 tiles of 128x128. LDS 144K: B dbuf, A2 dbuf, Pp.
// ph2 wave grid 2m x 4n: bf reads 2/ks (B-LDS amp 8x -> 2x); af[4] rolled from L2.
// ph4 (kh x zq) + wb[2][16] register-resident: verbatim R13.
__global__ __launch_bounds__(512, 2) void k_opm(
    const short* __restrict__ aTf, const short* __restrict__ bTf,
    const short* __restrict__ wbTf, const float* __restrict__ b_out,
    float* __restrict__ out) {
    __shared__ __align__(16) char smem[147456];
    int tid = threadIdx.x, lane = tid & 63, w = tid >> 6;
    int g = lane >> 4, r16 = lane & 15;
    int wm = w & 1, wn = w >> 1;     // ph2 roles: m-half, n-quarter
    int kh = w & 1, zq = w >> 1;     // ph4 roles: k-half, z-quarter

    int t0 = blockIdx.x * 36;
    const char* Ab = (const char*)aTf;
    const char* Bb = (const char*)bTf;

    // ---- issue B(t0)->buf0, B(t0+1)->buf1 staging (async)
    {
        const char* gB0 = Bb + (size_t)(t0 % 96) * 32768;
        const char* gB1 = Bb + (size_t)((t0 + 1) % 96) * 32768;
#pragma unroll
        for (int q = 0; q < 4; ++q) {
            __builtin_amdgcn_global_load_lds(
                (const __attribute__((address_space(1))) void*)(gB0 + q * 8192 + tid * 16),
                (__attribute__((address_space(3))) void*)(smem + q * 8192 + tid * 16), 16, 0, 0);
            __builtin_amdgcn_global_load_lds(
                (const __attribute__((address_space(1))) void*)(gB1 + q * 8192 + tid * 16),
                (__attribute__((address_space(3))) void*)(smem + 32768 + q * 8192 + tid * 16), 16, 0, 0);
        }
    }
    // ---- persistent wbT slice (z in [zq*32,+32), k in [kh*512,+512))
    bf16x8 wb[2][16];
#pragma unroll
    for (int zt = 0; zt < 2; ++zt)
#pragma unroll
        for (int ks2 = 0; ks2 < 16; ++ks2)
            wb[zt][ks2] = *(const bf16x8*)(wbTf +
                (((size_t)(zq * 2 + zt) * 32 + kh * 16 + ks2) * 64 + lane) * 8);

    int pR = tid >> 5;
    int zR = (tid & 31) * 4;
    float4 bo4 = *(const float4*)(b_out + zR);

    // af preload: tile t0, ks=0, 4 m-frags of this wave's m-half
    bf16x8 afc[4], afn[4];
    {
        const char* gA0 = Ab + (size_t)((t0 / 96) * 8 + wm * 4) * 4096;
#pragma unroll
        for (int mi = 0; mi < 4; ++mi)
            afc[mi] = *(const bf16x8*)(gA0 + mi * 4096 + lane * 16);
    }
    asm volatile("s_waitcnt vmcnt(0)" ::: "memory");
    __syncthreads();

    // ---- prologue: ph2(t0) from buf0 -> acc; ph3(t0) -> A2_0
    f32x4 acc[4][2] = {};
    {
        const char* gAc = Ab + (size_t)((t0 / 96) * 8 + wm * 4) * 4096;
        const char* gAn = Ab + (size_t)(((t0 + 1) / 96) * 8 + wm * 4) * 4096;
#pragma unroll
        for (int ks = 0; ks < 4; ++ks) {
            bf16x8 bf0 = *(const bf16x8*)(smem + (((wn * 2 + 0) * 4 + ks) * 64 + lane) * 16);
            bf16x8 bf1 = *(const bf16x8*)(smem + (((wn * 2 + 1) * 4 + ks) * 64 + lane) * 16);
#pragma unroll
            for (int mi = 0; mi < 4; ++mi)
                afn[mi] = (ks < 3) ? *(const bf16x8*)(gAc + mi * 4096 + (ks + 1) * 1024 + lane * 16)
                                   : *(const bf16x8*)(gAn + mi * 4096 + lane * 16);
            __builtin_amdgcn_s_setprio(1);
#pragma unroll
            for (int mi = 0; mi < 4; ++mi) {
                acc[mi][0] = __builtin_amdgcn_mfma_f32_16x16x32_bf16(bf0, afc[mi], acc[mi][0], 0, 0, 0);
                acc[mi][1] = __builtin_amdgcn_mfma_f32_16x16x32_bf16(bf1, afc[mi], acc[mi][1], 0, 0, 0);
            }
            __builtin_amdgcn_s_setprio(0);
#pragma unroll
            for (int mi = 0; mi < 4; ++mi) afc[mi] = afn[mi];
        }
    }
    lgkm_barrier();
#pragma unroll
    for (int mi = 0; mi < 4; ++mi)
#pragma unroll
        for (int ni = 0; ni < 2; ++ni) {
            int p = (wm * 2 + (mi >> 1)) * 4 + wn;
            int x = (mi & 1) * 16 + r16;
            int y0 = ni * 16 + g * 4;
            int byte = (p * 2048 + x * 64 + y0 * 2) ^ (((p & 7) ^ (x & 7)) << 4);
            short4 pk;
            pk.x = tobf16(acc[mi][ni][0]);
            pk.y = tobf16(acc[mi][ni][1]);
            pk.z = tobf16(acc[mi][ni][2]);
            pk.w = tobf16(acc[mi][ni][3]);
            *(short4*)(smem + 65536 + byte) = pk;
        }
    lgkm_barrier();   // A2_0 visible

    for (int it = 0; it < 36; ++it) {
        int t = t0 + it;
        bool hasN = (it < 35);
        int tc = t + 1;
        int tnn = (it < 34) ? t + 2 : t0 + 35;

        // ---- stage B(it+2) into buf (it&1)
        if (it < 34) {
            const char* gB = Bb + (size_t)((t + 2) % 96) * 32768;
            char* dst = smem + (it & 1) * 32768;
#pragma unroll
            for (int q = 0; q < 4; ++q)
                __builtin_amdgcn_global_load_lds(
                    (const __attribute__((address_space(1))) void*)(gB + q * 8192 + tid * 16),
                    (__attribute__((address_space(3))) void*)(dst + q * 8192 + tid * 16), 16, 0, 0);
        }

        const char* A2r = smem + 65536 + (it & 1) * 32768;
        const char* Bn  = smem + ((it + 1) & 1) * 32768;
        const char* gAc = Ab + (size_t)((tc / 96) * 8 + wm * 4) * 4096;
        const char* gAn = Ab + (size_t)((tnn / 96) * 8 + wm * 4) * 4096;

        // ---- merged compute: ph4(it) + ph2(it+1)
        f32x4 c0 = {0,0,0,0}, c1 = {0,0,0,0};
        f32x4 acc2[4][2] = {};
#pragma unroll
        for (int ks = 0; ks < 4; ++ks) {
            bf16x8 a2f0, a2f1, bf0, bf1;
            {
                int x = kh * 16 + ks * 4 + 0;
                a2f0 = *(const bf16x8*)(A2r + ((r16 * 2048 + x * 64 + g * 16)
                        ^ ((((r16 & 7) ^ (x & 7))) << 4)));
                x = kh * 16 + ks * 4 + 1;
                a2f1 = *(const bf16x8*)(A2r + ((r16 * 2048 + x * 64 + g * 16)
                        ^ ((((r16 & 7) ^ (x & 7))) << 4)));
            }
            if (hasN) {
                bf0 = *(const bf16x8*)(Bn + (((wn * 2 + 0) * 4 + ks) * 64 + lane) * 16);
                bf1 = *(const bf16x8*)(Bn + (((wn * 2 + 1) * 4 + ks) * 64 + lane) * 16);
            }
            __builtin_amdgcn_s_setprio(1);
            c0 = __builtin_amdgcn_mfma_f32_16x16x32_bf16(wb[0][ks * 4 + 0], a2f0, c0, 0, 0, 0);
            c1 = __builtin_amdgcn_mfma_f32_16x16x32_bf16(wb[1][ks * 4 + 0], a2f0, c1, 0, 0, 0);
            c0 = __builtin_amdgcn_mfma_f32_16x16x32_bf16(wb[0][ks * 4 + 1], a2f1, c0, 0, 0, 0);
            c1 = __builtin_amdgcn_mfma_f32_16x16x32_bf16(wb[1][ks * 4 + 1], a2f1, c1, 0, 0, 0);
            if (hasN) {
#pragma unroll
                for (int mi = 0; mi < 4; ++mi)
                    acc2[mi][0] = __builtin_amdgcn_mfma_f32_16x16x32_bf16(bf0, afc[mi], acc2[mi][0], 0, 0, 0);
            }
            __builtin_amdgcn_s_setprio(0);
            bf16x8 a2f2, a2f3;
            {
                int x = kh * 16 + ks * 4 + 2;
                a2f2 = *(const bf16x8*)(A2r + ((r16 * 2048 + x * 64 + g * 16)
                        ^ ((((r16 & 7) ^ (x & 7))) << 4)));
                x = kh * 16 + ks * 4 + 3;
                a2f3 = *(const bf16x8*)(A2r + ((r16 * 2048 + x * 64 + g * 16)
                        ^ ((((r16 & 7) ^ (x & 7))) << 4)));
            }
            if (hasN) {
#pragma unroll
                for (int mi = 0; mi < 4; ++mi)
                    afn[mi] = (ks < 3) ? *(const bf16x8*)(gAc + mi * 4096 + (ks + 1) * 1024 + lane * 16)
                                       : *(const bf16x8*)(gAn + mi * 4096 + lane * 16);
            }
            __builtin_amdgcn_s_setprio(1);
            c0 = __builtin_amdgcn_mfma_f32_16x16x32_bf16(wb[0][ks * 4 + 2], a2f2, c0, 0, 0, 0);
            c1 = __builtin_amdgcn_mfma_f32_16x16x32_bf16(wb[1][ks * 4 + 2], a2f2, c1, 0, 0, 0);
            c0 = __builtin_amdgcn_mfma_f32_16x16x32_bf16(wb[0][ks * 4 + 3], a2f3, c0, 0, 0, 0);
            c1 = __builtin_amdgcn_mfma_f32_16x16x32_bf16(wb[1][ks * 4 + 3], a2f3, c1, 0, 0, 0);
            if (hasN) {
#pragma unroll
                for (int mi = 0; mi < 4; ++mi)
                    acc2[mi][1] = __builtin_amdgcn_mfma_f32_16x16x32_bf16(bf1, afc[mi], acc2[mi][1], 0, 0, 0);
            }
            __builtin_amdgcn_s_setprio(0);
            if (hasN) {
#pragma unroll
                for (int mi = 0; mi < 4; ++mi) afc[mi] = afn[mi];
            }
        }

        // ---- Pp write: [kh][p=r16][z] f32 at [128K,144K), ^((r16&7)<<4)
        {
            int b0 = (kh * 8192 + r16 * 512 + (zq * 32 + g * 4) * 4) ^ ((r16 & 7) << 4);
            int b1 = (kh * 8192 + r16 * 512 + (zq * 32 + 16 + g * 4) * 4) ^ ((r16 & 7) << 4);
            *(f32x4*)(smem + 131072 + b0) = c0;
            *(f32x4*)(smem + 131072 + b1) = c1;
        }
        lgkm_barrier();   // Pp visible; A2r/Bn reads done

        // ---- ph3(it+1): acc2 -> A2 buf ((it+1)&1)
        if (hasN) {
            char* A2w = smem + 65536 + ((it + 1) & 1) * 32768;
#pragma unroll
            for (int mi = 0; mi < 4; ++mi)
#pragma unroll
                for (int ni = 0; ni < 2; ++ni) {
                    int p = (wm * 2 + (mi >> 1)) * 4 + wn;
                    int x = (mi & 1) * 16 + r16;
                    int y0 = ni * 16 + g * 4;
                    int byte = (p * 2048 + x * 64 + y0 * 2) ^ (((p & 7) ^ (x & 7)) << 4);
                    short4 pk;
                    pk.x = tobf16(acc2[mi][ni][0]);
                    pk.y = tobf16(acc2[mi][ni][1]);
                    pk.z = tobf16(acc2[mi][ni][2]);
                    pk.w = tobf16(acc2[mi][ni][3]);
                    *(short4*)(A2w + byte) = pk;
                }
        }

        // ---- reduce kh-halves + coalesced store for tile it
        {
            int base = (pR * 512 + zR * 4) ^ ((pR & 7) << 4);
            f32x4 v0 = *(const f32x4*)(smem + 131072 + base);
            f32x4 v1 = *(const f32x4*)(smem + 131072 + 8192 + base);
            f32x4 res;
            res[0] = (v0[0] + v1[0] + bo4.x) * (1.0f / 128.0f);
            res[1] = (v0[1] + v1[1] + bo4.y) * (1.0f / 128.0f);
            res[2] = (v0[2] + v1[2] + bo4.z) * (1.0f / 128.0f);
            res[3] = (v0[3] + v1[3] + bo4.w) * (1.0f / 128.0f);
            int bi4 = t / 96, bj4 = t % 96;
            int ig = bi4 * 4 + (pR >> 2);
            int jg = bj4 * 4 + (pR & 3);
            *(f32x4*)(out + ((size_t)ig * R_RES + jg) * CZ + zR) = res;
        }

        // ---- end barrier
        asm volatile("s_waitcnt vmcnt(0)" ::: "memory");
        __syncthreads();
    }
}

extern "C" void kernel_launch(void* const* d_in, const int* in_sizes, int n_in,
                              void* d_out, int out_size, void* d_ws, size_t ws_size,
                              hipStream_t stream) {
    const float* M     = (const float*)d_in[0];
    const float* ln_g  = (const float*)d_in[1];
    const float* ln_b  = (const float*)d_in[2];
    const float* w1    = (const float*)d_in[3];
    const float* b1    = (const float*)d_in[4];
    const float* w2    = (const float*)d_in[5];
    const float* b2    = (const float*)d_in[6];
    const float* w_out = (const float*)d_in[7];
    const float* b_out = (const float*)d_in[8];
    float* out = (float*)d_out;

    short* aTf  = (short*)d_ws;
    short* bTf  = aTf + 12288 * 128;
    short* wbTf = bTf + 12288 * 128;
    short* wcT  = wbTf + 128 * 1024;

    k_transpose_wout<<<dim3(16, 2), 256, 0, stream>>>(w_out, wbTf);
    k_pack_w12<<<64, 256, 0, stream>>>(w1, w2, wcT);
    k_ln_proj<<<768, 256, 0, stream>>>(M, ln_g, ln_b, b1, b2, wcT, aTf, bTf);
    k_opm<<<256, 512, 0, stream>>>(aTf, bTf, wbTf, b_out, out);
}

// Round 15
// 118.354 us; speedup vs baseline: 1.1720x; 1.1720x over previous
//
#include <hip/hip_runtime.h>
#include <hip/hip_bf16.h>

#define R_RES 384
#define S_SEQ 128
#define CM 256
#define CC 32
#define CZ 128

typedef __attribute__((ext_vector_type(8))) short bf16x8;
typedef __attribute__((ext_vector_type(4))) float f32x4;
typedef __attribute__((ext_vector_type(4))) int i32x4;

__device__ __forceinline__ short tobf16(float f) {
    union { __hip_bfloat16 h; short s; } u;
    u.h = __float2bfloat16(f);
    return u.s;
}

__device__ __forceinline__ void lgkm_barrier() {
    asm volatile("s_waitcnt lgkmcnt(0)" ::: "memory");
    __builtin_amdgcn_s_barrier();
    __builtin_amdgcn_sched_barrier(0);
}

// ---------------- kernel 0a: w_out (1024,128) f32 -> wbTf 16x16x32-B-frag tiled bf16 ------
__global__ void k_transpose_wout(const float* __restrict__ w_out, short* __restrict__ wbTf) {
    __shared__ float t[64][65];
    int k0 = blockIdx.x * 64;
    int z0 = blockIdx.y * 64;
    int tid = threadIdx.x;
    int c = tid & 63, rg = tid >> 6;
#pragma unroll
    for (int rr = 0; rr < 16; ++rr) {
        int kk = rg * 16 + rr;
        t[kk][c] = w_out[(size_t)(k0 + kk) * CZ + z0 + c];
    }
    __syncthreads();
#pragma unroll
    for (int l = 0; l < 2; ++l) {
        int id = l * 256 + tid;
        int f = id >> 6;
        int z16l = f >> 1, k32l = f & 1;
        int ln = id & 63;
        int zl = z16l * 16 + (ln & 15);
        int kl = k32l * 32 + (ln >> 4) * 8;
        bf16x8 pk;
#pragma unroll
        for (int j = 0; j < 8; ++j) pk[j] = tobf16(t[kl + j][zl]);
        int z16 = blockIdx.y * 4 + z16l;
        int k32 = blockIdx.x * 2 + k32l;
        *(bf16x8*)(wbTf + ((size_t)(z16 * 32 + k32) * 64 + ln) * 8) = pk;
    }
}

// ---------------- kernel 0b: pack w1|w2 (256,32) -> wcT (64,256) bf16 ----------------
__global__ void k_pack_w12(const float* __restrict__ w1, const float* __restrict__ w2,
                           short* __restrict__ wcT) {
    int idx = blockIdx.x * 256 + threadIdx.x;
    int k = idx >> 6, n = idx & 63;
    float v = (n < 32) ? w1[k * CC + n] : w2[k * CC + (n - 32)];
    wcT[n * CM + k] = tobf16(v);
}

// ---------------- kernel 1: LayerNorm + projections -> aTf, bTf fragment-tiled bf16 --------
__global__ __launch_bounds__(256) void k_ln_proj(
    const float* __restrict__ M, const float* __restrict__ ln_g, const float* __restrict__ ln_b,
    const float* __restrict__ b1, const float* __restrict__ b2,
    const short* __restrict__ wcT, short* __restrict__ aTf, short* __restrict__ bTf) {
    __shared__ short mnb[64 * 256];
    __shared__ short ab_s[2][32 * 72];
    int r = blockIdx.x >> 1;
    int s0 = (blockIdx.x & 1) * 64;
    int tid = threadIdx.x, lane = tid & 63, w = tid >> 6;
    int g = lane >> 4, r16 = lane & 15;
    float4 gv = *(const float4*)(ln_g + lane * 4);
    float4 bv = *(const float4*)(ln_b + lane * 4);
    for (int it = 0; it < 16; ++it) {
        int sl = it * 4 + w;
        float4 v = *(const float4*)(M + ((size_t)(s0 + sl) * R_RES + r) * CM + lane * 4);
        float sum = v.x + v.y + v.z + v.w;
        float sq = v.x * v.x + v.y * v.y + v.z * v.z + v.w * v.w;
#pragma unroll
        for (int off = 32; off; off >>= 1) {
            sum += __shfl_xor(sum, off);
            sq  += __shfl_xor(sq, off);
        }
        float mu = sum * (1.0f / 256.0f);
        float var = sq * (1.0f / 256.0f) - mu * mu;
        float rstd = rsqrtf(var + 1e-5f);
        short4 mnp;
        mnp.x = tobf16((v.x - mu) * rstd * gv.x + bv.x);
        mnp.y = tobf16((v.y - mu) * rstd * gv.y + bv.y);
        mnp.z = tobf16((v.z - mu) * rstd * gv.z + bv.z);
        mnp.w = tobf16((v.w - mu) * rstd * gv.w + bv.w);
        int byte = sl * 512 + lane * 8;
        byte ^= ((sl & 7) << 4);
        *(short4*)((char*)mnb + byte) = mnp;
    }
    __syncthreads();
    f32x4 acc[4] = {{0,0,0,0},{0,0,0,0},{0,0,0,0},{0,0,0,0}};
    int srow = w * 16 + r16;
#pragma unroll
    for (int ks = 0; ks < 8; ++ks) {
        int byte = srow * 512 + ks * 64 + g * 16;
        byte ^= ((srow & 7) << 4);
        bf16x8 af = *(const bf16x8*)((const char*)mnb + byte);
#pragma unroll
        for (int nt = 0; nt < 4; ++nt) {
            bf16x8 bf = *(const bf16x8*)(wcT + (nt * 16 + r16) * CM + ks * 32 + g * 8);
            acc[nt] = __builtin_amdgcn_mfma_f32_16x16x32_bf16(af, bf, acc[nt], 0, 0, 0);
        }
    }
#pragma unroll
    for (int nt = 0; nt < 4; ++nt) {
        int n = nt * 16 + r16;
        int x = n & 31, sel = n >> 5;
        float bias = sel ? b2[x] : b1[x];
#pragma unroll
        for (int rr = 0; rr < 4; ++rr) {
            int sl = w * 16 + g * 4 + rr;
            ab_s[sel][x * 72 + sl] = tobf16(acc[nt][rr] + bias);
        }
    }
    __syncthreads();
    int piece = tid >> 6;
    int fl = piece >> 1, kl = piece & 1;
    int ln = tid & 63;
    int x = fl * 16 + (ln & 15);
    int s_loc = kl * 32 + (ln >> 4) * 8;
    i32x4 va = *(const i32x4*)((const char*)ab_s[0] + (x * 72 + s_loc) * 2);
    i32x4 vb = *(const i32x4*)((const char*)ab_s[1] + (x * 72 + s_loc) * 2);
    size_t off = ((((size_t)r * 2 + fl) * 4 + (s0 >> 5) + kl) * 64 + ln) * 16;
    *(i32x4*)((char*)aTf + off) = va;
    *(i32x4*)((char*)bTf + off) = vb;
}

// ---------------- kernel 2: persistent cross-tile-pipelined fused kernel (v3) ----------------
// 256 blocks x 512 thr, 36 tiles of 128x128. LDS 144K: B dbuf, A2 dbuf, Pp.
// ph2 wave grid 4m x 2n: 4 bf + 2 af per ks -> 8 MFMA (B-LDS amp 4x). af read fresh (no roll
// registers -> no spill). ph4 (kh x zq) + wb[2][16] register-resident: verbatim R13.
__global__ __launch_bounds__(512, 2) void k_opm(
    const short* __restrict__ aTf, const short* __restrict__ bTf,
    const short* __restrict__ wbTf, const float* __restrict__ b_out,
    float* __restrict__ out) {
    __shared__ __align__(16) char smem[147456];
    int tid = threadIdx.x, lane = tid & 63, w = tid >> 6;
    int g = lane >> 4, r16 = lane & 15;
    int wm = w >> 1, wn = w & 1;     // ph2 roles: m-quarter (32 rows), n-half (4 frags)
    int kh = w & 1, zq = w >> 1;     // ph4 roles: k-half, z-quarter

    int t0 = blockIdx.x * 36;
    const char* Ab = (const char*)aTf;
    const char* Bb = (const char*)bTf;

    // ---- issue B(t0)->buf0, B(t0+1)->buf1 staging (async)
    {
        const char* gB0 = Bb + (size_t)(t0 % 96) * 32768;
        const char* gB1 = Bb + (size_t)((t0 + 1) % 96) * 32768;
#pragma unroll
        for (int q = 0; q < 4; ++q) {
            __builtin_amdgcn_global_load_lds(
                (const __attribute__((address_space(1))) void*)(gB0 + q * 8192 + tid * 16),
                (__attribute__((address_space(3))) void*)(smem + q * 8192 + tid * 16), 16, 0, 0);
            __builtin_amdgcn_global_load_lds(
                (const __attribute__((address_space(1))) void*)(gB1 + q * 8192 + tid * 16),
                (__attribute__((address_space(3))) void*)(smem + 32768 + q * 8192 + tid * 16), 16, 0, 0);
        }
    }
    // ---- persistent wbT slice (z in [zq*32,+32), k in [kh*512,+512))
    bf16x8 wb[2][16];
#pragma unroll
    for (int zt = 0; zt < 2; ++zt)
#pragma unroll
        for (int ks2 = 0; ks2 < 16; ++ks2)
            wb[zt][ks2] = *(const bf16x8*)(wbTf +
                (((size_t)(zq * 2 + zt) * 32 + kh * 16 + ks2) * 64 + lane) * 8);

    int pR = tid >> 5;
    int zR = (tid & 31) * 4;
    float4 bo4 = *(const float4*)(b_out + zR);

    asm volatile("s_waitcnt vmcnt(0)" ::: "memory");
    __syncthreads();

    // ---- prologue: ph2(t0) from buf0 -> acc; ph3(t0) -> A2_0
    f32x4 acc[2][4] = {};
    {
        const char* gAc = Ab + (size_t)((t0 / 96) * 8 + wm * 2) * 4096;
#pragma unroll
        for (int ks = 0; ks < 4; ++ks) {
            bf16x8 afc0 = *(const bf16x8*)(gAc + ks * 1024 + lane * 16);
            bf16x8 afc1 = *(const bf16x8*)(gAc + 4096 + ks * 1024 + lane * 16);
            bf16x8 bf[4];
#pragma unroll
            for (int ni = 0; ni < 4; ++ni)
                bf[ni] = *(const bf16x8*)(smem + (((wn * 4 + ni) * 4 + ks) * 64 + lane) * 16);
            __builtin_amdgcn_s_setprio(1);
#pragma unroll
            for (int ni = 0; ni < 4; ++ni) {
                acc[0][ni] = __builtin_amdgcn_mfma_f32_16x16x32_bf16(bf[ni], afc0, acc[0][ni], 0, 0, 0);
                acc[1][ni] = __builtin_amdgcn_mfma_f32_16x16x32_bf16(bf[ni], afc1, acc[1][ni], 0, 0, 0);
            }
            __builtin_amdgcn_s_setprio(0);
        }
    }
    lgkm_barrier();
#pragma unroll
    for (int mi = 0; mi < 2; ++mi)
#pragma unroll
        for (int ni = 0; ni < 4; ++ni) {
            int p = wm * 4 + wn * 2 + (ni >> 1);
            int x = mi * 16 + r16;
            int y0 = (ni & 1) * 16 + g * 4;
            int byte = (p * 2048 + x * 64 + y0 * 2) ^ (((p & 7) ^ (x & 7)) << 4);
            short4 pk;
            pk.x = tobf16(acc[mi][ni][0]);
            pk.y = tobf16(acc[mi][ni][1]);
            pk.z = tobf16(acc[mi][ni][2]);
            pk.w = tobf16(acc[mi][ni][3]);
            *(short4*)(smem + 65536 + byte) = pk;
        }
    lgkm_barrier();   // A2_0 visible

    for (int it = 0; it < 36; ++it) {
        int t = t0 + it;
        bool hasN = (it < 35);
        int tc = (it < 35) ? t + 1 : t;

        // ---- stage B(it+2) into buf (it&1)
        if (it < 34) {
            const char* gB = Bb + (size_t)((t + 2) % 96) * 32768;
            char* dst = smem + (it & 1) * 32768;
#pragma unroll
            for (int q = 0; q < 4; ++q)
                __builtin_amdgcn_global_load_lds(
                    (const __attribute__((address_space(1))) void*)(gB + q * 8192 + tid * 16),
                    (__attribute__((address_space(3))) void*)(dst + q * 8192 + tid * 16), 16, 0, 0);
        }

        const char* A2r = smem + 65536 + (it & 1) * 32768;
        const char* Bn  = smem + ((it + 1) & 1) * 32768;
        const char* gAc = Ab + (size_t)((tc / 96) * 8 + wm * 2) * 4096;

        // ---- merged compute: ph4(it) + ph2(it+1)
        f32x4 c0 = {0,0,0,0}, c1 = {0,0,0,0};
        f32x4 acc2[2][4] = {};
#pragma unroll
        for (int ks = 0; ks < 4; ++ks) {
            // issue ph2 af loads first (L2 latency lead), then LDS reads
            bf16x8 afc0, afc1, bf[4];
            if (hasN) {
                afc0 = *(const bf16x8*)(gAc + ks * 1024 + lane * 16);
                afc1 = *(const bf16x8*)(gAc + 4096 + ks * 1024 + lane * 16);
#pragma unroll
                for (int ni = 0; ni < 4; ++ni)
                    bf[ni] = *(const bf16x8*)(Bn + (((wn * 4 + ni) * 4 + ks) * 64 + lane) * 16);
            }
            bf16x8 a2f0, a2f1, a2f2, a2f3;
            {
                int x = kh * 16 + ks * 4 + 0;
                a2f0 = *(const bf16x8*)(A2r + ((r16 * 2048 + x * 64 + g * 16)
                        ^ ((((r16 & 7) ^ (x & 7))) << 4)));
                x = kh * 16 + ks * 4 + 1;
                a2f1 = *(const bf16x8*)(A2r + ((r16 * 2048 + x * 64 + g * 16)
                        ^ ((((r16 & 7) ^ (x & 7))) << 4)));
                x = kh * 16 + ks * 4 + 2;
                a2f2 = *(const bf16x8*)(A2r + ((r16 * 2048 + x * 64 + g * 16)
                        ^ ((((r16 & 7) ^ (x & 7))) << 4)));
                x = kh * 16 + ks * 4 + 3;
                a2f3 = *(const bf16x8*)(A2r + ((r16 * 2048 + x * 64 + g * 16)
                        ^ ((((r16 & 7) ^ (x & 7))) << 4)));
            }
            __builtin_amdgcn_s_setprio(1);
            c0 = __builtin_amdgcn_mfma_f32_16x16x32_bf16(wb[0][ks * 4 + 0], a2f0, c0, 0, 0, 0);
            c1 = __builtin_amdgcn_mfma_f32_16x16x32_bf16(wb[1][ks * 4 + 0], a2f0, c1, 0, 0, 0);
            c0 = __builtin_amdgcn_mfma_f32_16x16x32_bf16(wb[0][ks * 4 + 1], a2f1, c0, 0, 0, 0);
            c1 = __builtin_amdgcn_mfma_f32_16x16x32_bf16(wb[1][ks * 4 + 1], a2f1, c1, 0, 0, 0);
            if (hasN) {
#pragma unroll
                for (int ni = 0; ni < 4; ++ni)
                    acc2[0][ni] = __builtin_amdgcn_mfma_f32_16x16x32_bf16(bf[ni], afc0, acc2[0][ni], 0, 0, 0);
            }
            c0 = __builtin_amdgcn_mfma_f32_16x16x32_bf16(wb[0][ks * 4 + 2], a2f2, c0, 0, 0, 0);
            c1 = __builtin_amdgcn_mfma_f32_16x16x32_bf16(wb[1][ks * 4 + 2], a2f2, c1, 0, 0, 0);
            c0 = __builtin_amdgcn_mfma_f32_16x16x32_bf16(wb[0][ks * 4 + 3], a2f3, c0, 0, 0, 0);
            c1 = __builtin_amdgcn_mfma_f32_16x16x32_bf16(wb[1][ks * 4 + 3], a2f3, c1, 0, 0, 0);
            if (hasN) {
#pragma unroll
                for (int ni = 0; ni < 4; ++ni)
                    acc2[1][ni] = __builtin_amdgcn_mfma_f32_16x16x32_bf16(bf[ni], afc1, acc2[1][ni], 0, 0, 0);
            }
            __builtin_amdgcn_s_setprio(0);
        }

        // ---- Pp write: [kh][p=r16][z] f32 at [128K,144K), ^((r16&7)<<4)
        {
            int b0 = (kh * 8192 + r16 * 512 + (zq * 32 + g * 4) * 4) ^ ((r16 & 7) << 4);
            int b1 = (kh * 8192 + r16 * 512 + (zq * 32 + 16 + g * 4) * 4) ^ ((r16 & 7) << 4);
            *(f32x4*)(smem + 131072 + b0) = c0;
            *(f32x4*)(smem + 131072 + b1) = c1;
        }
        lgkm_barrier();   // Pp visible; A2r/Bn reads done

        // ---- ph3(it+1): acc2 -> A2 buf ((it+1)&1)
        if (hasN) {
            char* A2w = smem + 65536 + ((it + 1) & 1) * 32768;
#pragma unroll
            for (int mi = 0; mi < 2; ++mi)
#pragma unroll
                for (int ni = 0; ni < 4; ++ni) {
                    int p = wm * 4 + wn * 2 + (ni >> 1);
                    int x = mi * 16 + r16;
                    int y0 = (ni & 1) * 16 + g * 4;
                    int byte = (p * 2048 + x * 64 + y0 * 2) ^ (((p & 7) ^ (x & 7)) << 4);
                    short4 pk;
                    pk.x = tobf16(acc2[mi][ni][0]);
                    pk.y = tobf16(acc2[mi][ni][1]);
                    pk.z = tobf16(acc2[mi][ni][2]);
                    pk.w = tobf16(acc2[mi][ni][3]);
                    *(short4*)(A2w + byte) = pk;
                }
        }

        // ---- reduce kh-halves + coalesced store for tile it
        {
            int base = (pR * 512 + zR * 4) ^ ((pR & 7) << 4);
            f32x4 v0 = *(const f32x4*)(smem + 131072 + base);
            f32x4 v1 = *(const f32x4*)(smem + 131072 + 8192 + base);
            f32x4 res;
            res[0] = (v0[0] + v1[0] + bo4.x) * (1.0f / 128.0f);
            res[1] = (v0[1] + v1[1] + bo4.y) * (1.0f / 128.0f);
            res[2] = (v0[2] + v1[2] + bo4.z) * (1.0f / 128.0f);
            res[3] = (v0[3] + v1[3] + bo4.w) * (1.0f / 128.0f);
            int bi4 = t / 96, bj4 = t % 96;
            int ig = bi4 * 4 + (pR >> 2);
            int jg = bj4 * 4 + (pR & 3);
            *(f32x4*)(out + ((size_t)ig * R_RES + jg) * CZ + zR) = res;
        }

        // ---- end barrier
        asm volatile("s_waitcnt vmcnt(0)" ::: "memory");
        __syncthreads();
    }
}

extern "C" void kernel_launch(void* const* d_in, const int* in_sizes, int n_in,
                              void* d_out, int out_size, void* d_ws, size_t ws_size,
                              hipStream_t stream) {
    const float* M     = (const float*)d_in[0];
    const float* ln_g  = (const float*)d_in[1];
    const float* ln_b  = (const float*)d_in[2];
    const float* w1    = (const float*)d_in[3];
    const float* b1    = (const float*)d_in[4];
    const float* w2    = (const float*)d_in[5];
    const float* b2    = (const float*)d_in[6];
    const float* w_out = (const float*)d_in[7];
    const float* b_out = (const float*)d_in[8];
    float* out = (float*)d_out;

    short* aTf  = (short*)d_ws;
    short* bTf  = aTf + 12288 * 128;
    short* wbTf = bTf + 12288 * 128;
    short* wcT  = wbTf + 128 * 1024;

    k_transpose_wout<<<dim3(16, 2), 256, 0, stream>>>(w_out, wbTf);
    k_pack_w12<<<64, 256, 0, stream>>>(w1, w2, wcT);
    k_ln_proj<<<768, 256, 0, stream>>>(M, ln_g, ln_b, b1, b2, wcT, aTf, bTf);
    k_opm<<<256, 512, 0, stream>>>(aTf, bTf, wbTf, b_out, out);
}

// Round 16
// 117.938 us; speedup vs baseline: 1.1761x; 1.0035x over previous
//
#include <hip/hip_runtime.h>
#include <hip/hip_bf16.h>

#define R_RES 384
#define S_SEQ 128
#define CM 256
#define CC 32
#define CZ 128

typedef __attribute__((ext_vector_type(8))) short bf16x8;
typedef __attribute__((ext_vector_type(4))) float f32x4;
typedef __attribute__((ext_vector_type(4))) int i32x4;

__device__ __forceinline__ short tobf16(float f) {
    union { __hip_bfloat16 h; short s; } u;
    u.h = __float2bfloat16(f);
    return u.s;
}

__device__ __forceinline__ void lgkm_barrier() {
    asm volatile("s_waitcnt lgkmcnt(0)" ::: "memory");
    __builtin_amdgcn_s_barrier();
    __builtin_amdgcn_sched_barrier(0);
}

// ---------------- kernel 0a: w_out (1024,128) f32 -> wbTf 16x16x32-B-frag tiled bf16 ------
// frag(z16, k32) lane l: z = z16*16 + (l&15), k = k32*32 + (l>>4)*8 + j
__global__ void k_transpose_wout(const float* __restrict__ w_out, short* __restrict__ wbTf) {
    __shared__ float t[64][65];
    int k0 = blockIdx.x * 64;
    int z0 = blockIdx.y * 64;
    int tid = threadIdx.x;
    int c = tid & 63, rg = tid >> 6;
#pragma unroll
    for (int rr = 0; rr < 16; ++rr) {
        int kk = rg * 16 + rr;
        t[kk][c] = w_out[(size_t)(k0 + kk) * CZ + z0 + c];
    }
    __syncthreads();
#pragma unroll
    for (int l = 0; l < 2; ++l) {
        int id = l * 256 + tid;
        int f = id >> 6;
        int z16l = f >> 1, k32l = f & 1;
        int ln = id & 63;
        int zl = z16l * 16 + (ln & 15);
        int kl = k32l * 32 + (ln >> 4) * 8;
        bf16x8 pk;
#pragma unroll
        for (int j = 0; j < 8; ++j) pk[j] = tobf16(t[kl + j][zl]);
        int z16 = blockIdx.y * 4 + z16l;
        int k32 = blockIdx.x * 2 + k32l;
        *(bf16x8*)(wbTf + ((size_t)(z16 * 32 + k32) * 64 + ln) * 8) = pk;
    }
}

// ---------------- kernel 0b: pack w1|w2 (256,32) -> wcT (64,256) bf16 ----------------
__global__ void k_pack_w12(const float* __restrict__ w1, const float* __restrict__ w2,
                           short* __restrict__ wcT) {
    int idx = blockIdx.x * 256 + threadIdx.x;
    int k = idx >> 6, n = idx & 63;
    float v = (n < 32) ? w1[k * CC + n] : w2[k * CC + (n - 32)];
    wcT[n * CM + k] = tobf16(v);
}

// ---------------- kernel 1: LayerNorm + projections -> aTf, bTf fragment-tiled bf16 --------
__global__ __launch_bounds__(256) void k_ln_proj(
    const float* __restrict__ M, const float* __restrict__ ln_g, const float* __restrict__ ln_b,
    const float* __restrict__ b1, const float* __restrict__ b2,
    const short* __restrict__ wcT, short* __restrict__ aTf, short* __restrict__ bTf) {
    __shared__ short mnb[64 * 256];
    __shared__ short ab_s[2][32 * 72];
    int r = blockIdx.x >> 1;
    int s0 = (blockIdx.x & 1) * 64;
    int tid = threadIdx.x, lane = tid & 63, w = tid >> 6;
    int g = lane >> 4, r16 = lane & 15;
    float4 gv = *(const float4*)(ln_g + lane * 4);
    float4 bv = *(const float4*)(ln_b + lane * 4);
    for (int it = 0; it < 16; ++it) {
        int sl = it * 4 + w;
        float4 v = *(const float4*)(M + ((size_t)(s0 + sl) * R_RES + r) * CM + lane * 4);
        float sum = v.x + v.y + v.z + v.w;
        float sq = v.x * v.x + v.y * v.y + v.z * v.z + v.w * v.w;
#pragma unroll
        for (int off = 32; off; off >>= 1) {
            sum += __shfl_xor(sum, off);
            sq  += __shfl_xor(sq, off);
        }
        float mu = sum * (1.0f / 256.0f);
        float var = sq * (1.0f / 256.0f) - mu * mu;
        float rstd = rsqrtf(var + 1e-5f);
        short4 mnp;
        mnp.x = tobf16((v.x - mu) * rstd * gv.x + bv.x);
        mnp.y = tobf16((v.y - mu) * rstd * gv.y + bv.y);
        mnp.z = tobf16((v.z - mu) * rstd * gv.z + bv.z);
        mnp.w = tobf16((v.w - mu) * rstd * gv.w + bv.w);
        int byte = sl * 512 + lane * 8;
        byte ^= ((sl & 7) << 4);
        *(short4*)((char*)mnb + byte) = mnp;
    }
    __syncthreads();
    f32x4 acc[4] = {{0,0,0,0},{0,0,0,0},{0,0,0,0},{0,0,0,0}};
    int srow = w * 16 + r16;
#pragma unroll
    for (int ks = 0; ks < 8; ++ks) {
        int byte = srow * 512 + ks * 64 + g * 16;
        byte ^= ((srow & 7) << 4);
        bf16x8 af = *(const bf16x8*)((const char*)mnb + byte);
#pragma unroll
        for (int nt = 0; nt < 4; ++nt) {
            bf16x8 bf = *(const bf16x8*)(wcT + (nt * 16 + r16) * CM + ks * 32 + g * 8);
            acc[nt] = __builtin_amdgcn_mfma_f32_16x16x32_bf16(af, bf, acc[nt], 0, 0, 0);
        }
    }
#pragma unroll
    for (int nt = 0; nt < 4; ++nt) {
        int n = nt * 16 + r16;
        int x = n & 31, sel = n >> 5;
        float bias = sel ? b2[x] : b1[x];
#pragma unroll
        for (int rr = 0; rr < 4; ++rr) {
            int sl = w * 16 + g * 4 + rr;
            ab_s[sel][x * 72 + sl] = tobf16(acc[nt][rr] + bias);
        }
    }
    __syncthreads();
    int piece = tid >> 6;
    int fl = piece >> 1, kl = piece & 1;
    int ln = tid & 63;
    int x = fl * 16 + (ln & 15);
    int s_loc = kl * 32 + (ln >> 4) * 8;
    i32x4 va = *(const i32x4*)((const char*)ab_s[0] + (x * 72 + s_loc) * 2);
    i32x4 vb = *(const i32x4*)((const char*)ab_s[1] + (x * 72 + s_loc) * 2);
    size_t off = ((((size_t)r * 2 + fl) * 4 + (s0 >> 5) + kl) * 64 + ln) * 16;
    *(i32x4*)((char*)aTf + off) = va;
    *(i32x4*)((char*)bTf + off) = vb;
}

// ---------------- kernel 2: persistent single-barrier pipelined fused kernel (v4) ----------
// 256 blocks x 512 thr, 36 tiles of 128x128. LDS 128K: B dbuf [0,64K), A2 dbuf [64K,128K).
// ph4 role: wave w owns z-frag w (16 z) x FULL k=1024 -> wb[32] resident (128 VGPR),
// output final per wave: NO Pp, NO reduce. ONE barrier per iteration.
// Iter: {stage B(it+2) || ph4(it) || ph2(it+1) || ph3(it+1) || store(it)} -> vm+lgkm barrier.
__global__ __launch_bounds__(512, 2) void k_opm(
    const short* __restrict__ aTf, const short* __restrict__ bTf,
    const short* __restrict__ wbTf, const float* __restrict__ b_out,
    float* __restrict__ out) {
    __shared__ __align__(16) char smem[131072];
    int tid = threadIdx.x, lane = tid & 63, w = tid >> 6;
    int g = lane >> 4, r16 = lane & 15;
    int wm = w >> 1, wn = w & 1;     // ph2 roles: m-quarter, n-half

    int t0 = blockIdx.x * 36;
    const char* Ab = (const char*)aTf;
    const char* Bb = (const char*)bTf;

    // ---- stage B(t0)->buf0, B(t0+1)->buf1 (async)
    {
        const char* gB0 = Bb + (size_t)(t0 % 96) * 32768;
        const char* gB1 = Bb + (size_t)((t0 + 1) % 96) * 32768;
#pragma unroll
        for (int q = 0; q < 4; ++q) {
            __builtin_amdgcn_global_load_lds(
                (const __attribute__((address_space(1))) void*)(gB0 + q * 8192 + tid * 16),
                (__attribute__((address_space(3))) void*)(smem + q * 8192 + tid * 16), 16, 0, 0);
            __builtin_amdgcn_global_load_lds(
                (const __attribute__((address_space(1))) void*)(gB1 + q * 8192 + tid * 16),
                (__attribute__((address_space(3))) void*)(smem + 32768 + q * 8192 + tid * 16), 16, 0, 0);
        }
    }
    // ---- persistent wbT slice: z-frag w (16 z), ALL k (32 k32-frags). 128 VGPR, static idx.
    bf16x8 wb[32];
#pragma unroll
    for (int k32 = 0; k32 < 32; ++k32)
        wb[k32] = *(const bf16x8*)(wbTf + (((size_t)w * 32 + k32) * 64 + lane) * 8);

    int zb = w * 16 + g * 4;             // this thread's z-quad base
    float4 bo4 = *(const float4*)(b_out + zb);

    asm volatile("s_waitcnt vmcnt(0)" ::: "memory");
    __syncthreads();

    // ---- prologue: ph2(t0) from buf0 -> acc; ph3(t0) -> A2 buf0
    f32x4 acc[2][4] = {};
    {
        const char* gAc = Ab + (size_t)((t0 / 96) * 8 + wm * 2) * 4096;
#pragma unroll
        for (int ks = 0; ks < 4; ++ks) {
            bf16x8 afc0 = *(const bf16x8*)(gAc + ks * 1024 + lane * 16);
            bf16x8 afc1 = *(const bf16x8*)(gAc + 4096 + ks * 1024 + lane * 16);
            bf16x8 bf[4];
#pragma unroll
            for (int ni = 0; ni < 4; ++ni)
                bf[ni] = *(const bf16x8*)(smem + (((wn * 4 + ni) * 4 + ks) * 64 + lane) * 16);
            __builtin_amdgcn_s_setprio(1);
#pragma unroll
            for (int ni = 0; ni < 4; ++ni) {
                acc[0][ni] = __builtin_amdgcn_mfma_f32_16x16x32_bf16(bf[ni], afc0, acc[0][ni], 0, 0, 0);
                acc[1][ni] = __builtin_amdgcn_mfma_f32_16x16x32_bf16(bf[ni], afc1, acc[1][ni], 0, 0, 0);
            }
            __builtin_amdgcn_s_setprio(0);
        }
    }
    lgkm_barrier();
#pragma unroll
    for (int mi = 0; mi < 2; ++mi)
#pragma unroll
        for (int ni = 0; ni < 4; ++ni) {
            int p = wm * 4 + wn * 2 + (ni >> 1);
            int x = mi * 16 + r16;
            int y0 = (ni & 1) * 16 + g * 4;
            int byte = (p * 2048 + x * 64 + y0 * 2) ^ (((p & 7) ^ (x & 7)) << 4);
            short4 pk;
            pk.x = tobf16(acc[mi][ni][0]);
            pk.y = tobf16(acc[mi][ni][1]);
            pk.z = tobf16(acc[mi][ni][2]);
            pk.w = tobf16(acc[mi][ni][3]);
            *(short4*)(smem + 65536 + byte) = pk;
        }
    lgkm_barrier();   // A2_0 visible

    int abase = r16 * 2048 + g * 16;
    int akey = (r16 & 7) << 4;

    for (int it = 0; it < 36; ++it) {
        int t = t0 + it;
        bool hasN = (it < 35);
        int tc = hasN ? t + 1 : t;

        // ---- stage B(it+2) into buf (it&1) (WAR-safe: ph2(it) read it last iter, barrier passed)
        if (it < 34) {
            const char* gB = Bb + (size_t)((t + 2) % 96) * 32768;
            char* dst = smem + (it & 1) * 32768;
#pragma unroll
            for (int q = 0; q < 4; ++q)
                __builtin_amdgcn_global_load_lds(
                    (const __attribute__((address_space(1))) void*)(gB + q * 8192 + tid * 16),
                    (__attribute__((address_space(3))) void*)(dst + q * 8192 + tid * 16), 16, 0, 0);
        }

        const char* A2r = smem + 65536 + (it & 1) * 32768;
        const char* Bn  = smem + ((it + 1) & 1) * 32768;
        const char* gAc = Ab + (size_t)((tc / 96) * 8 + wm * 2) * 4096;

        // ---- merged compute: ph4(it) full-k (32 MFMA, c0/c1 chains) + ph2(it+1) (32 MFMA)
        f32x4 c0 = {0,0,0,0}, c1 = {0,0,0,0};
        f32x4 acc2[2][4] = {};
#pragma unroll
        for (int kq = 0; kq < 8; ++kq) {
            bf16x8 a2f0 = *(const bf16x8*)(A2r + ((abase + (kq * 4 + 0) * 64) ^ (akey ^ ((((kq * 4 + 0) & 7)) << 4))));
            bf16x8 a2f1 = *(const bf16x8*)(A2r + ((abase + (kq * 4 + 1) * 64) ^ (akey ^ ((((kq * 4 + 1) & 7)) << 4))));
            bf16x8 a2f2 = *(const bf16x8*)(A2r + ((abase + (kq * 4 + 2) * 64) ^ (akey ^ ((((kq * 4 + 2) & 7)) << 4))));
            bf16x8 a2f3 = *(const bf16x8*)(A2r + ((abase + (kq * 4 + 3) * 64) ^ (akey ^ ((((kq * 4 + 3) & 7)) << 4))));
            bf16x8 afc0, afc1, bf[4];
            if (hasN && kq < 4) {
                afc0 = *(const bf16x8*)(gAc + kq * 1024 + lane * 16);
                afc1 = *(const bf16x8*)(gAc + 4096 + kq * 1024 + lane * 16);
#pragma unroll
                for (int ni = 0; ni < 4; ++ni)
                    bf[ni] = *(const bf16x8*)(Bn + (((wn * 4 + ni) * 4 + kq) * 64 + lane) * 16);
            }
            __builtin_amdgcn_s_setprio(1);
            c0 = __builtin_amdgcn_mfma_f32_16x16x32_bf16(wb[kq * 4 + 0], a2f0, c0, 0, 0, 0);
            c1 = __builtin_amdgcn_mfma_f32_16x16x32_bf16(wb[kq * 4 + 1], a2f1, c1, 0, 0, 0);
            c0 = __builtin_amdgcn_mfma_f32_16x16x32_bf16(wb[kq * 4 + 2], a2f2, c0, 0, 0, 0);
            c1 = __builtin_amdgcn_mfma_f32_16x16x32_bf16(wb[kq * 4 + 3], a2f3, c1, 0, 0, 0);
            if (hasN && kq < 4) {
#pragma unroll
                for (int ni = 0; ni < 4; ++ni)
                    acc2[0][ni] = __builtin_amdgcn_mfma_f32_16x16x32_bf16(bf[ni], afc0, acc2[0][ni], 0, 0, 0);
#pragma unroll
                for (int ni = 0; ni < 4; ++ni)
                    acc2[1][ni] = __builtin_amdgcn_mfma_f32_16x16x32_bf16(bf[ni], afc1, acc2[1][ni], 0, 0, 0);
            }
            __builtin_amdgcn_s_setprio(0);
        }

        // ---- ph3(it+1): acc2 -> A2 buf ((it+1)&1)
        if (hasN) {
            char* A2w = smem + 65536 + ((it + 1) & 1) * 32768;
#pragma unroll
            for (int mi = 0; mi < 2; ++mi)
#pragma unroll
                for (int ni = 0; ni < 4; ++ni) {
                    int p = wm * 4 + wn * 2 + (ni >> 1);
                    int x = mi * 16 + r16;
                    int y0 = (ni & 1) * 16 + g * 4;
                    int byte = (p * 2048 + x * 64 + y0 * 2) ^ (((p & 7) ^ (x & 7)) << 4);
                    short4 pk;
                    pk.x = tobf16(acc2[mi][ni][0]);
                    pk.y = tobf16(acc2[mi][ni][1]);
                    pk.z = tobf16(acc2[mi][ni][2]);
                    pk.w = tobf16(acc2[mi][ni][3]);
                    *(short4*)(A2w + byte) = pk;
                }
        }

        // ---- epilogue tile it: final out from c0+c1 (p = r16, z = zb + rr)
        {
            int bi4 = t / 96, bj4 = t % 96;
            int ig = bi4 * 4 + (r16 >> 2);
            int jg = bj4 * 4 + (r16 & 3);
            f32x4 res;
            res[0] = (c0[0] + c1[0] + bo4.x) * (1.0f / 128.0f);
            res[1] = (c0[1] + c1[1] + bo4.y) * (1.0f / 128.0f);
            res[2] = (c0[2] + c1[2] + bo4.z) * (1.0f / 128.0f);
            res[3] = (c0[3] + c1[3] + bo4.w) * (1.0f / 128.0f);
            *(f32x4*)(out + ((size_t)ig * R_RES + jg) * CZ + zb) = res;
        }

        // ---- single end barrier: A2(it+1) + B staging visible for next iteration
        asm volatile("s_waitcnt vmcnt(0)" ::: "memory");
        __syncthreads();
    }
}

extern "C" void kernel_launch(void* const* d_in, const int* in_sizes, int n_in,
                              void* d_out, int out_size, void* d_ws, size_t ws_size,
                              hipStream_t stream) {
    const float* M     = (const float*)d_in[0];
    const float* ln_g  = (const float*)d_in[1];
    const float* ln_b  = (const float*)d_in[2];
    const float* w1    = (const float*)d_in[3];
    const float* b1    = (const float*)d_in[4];
    const float* w2    = (const float*)d_in[5];
    const float* b2    = (const float*)d_in[6];
    const float* w_out = (const float*)d_in[7];
    const float* b_out = (const float*)d_in[8];
    float* out = (float*)d_out;

    short* aTf  = (short*)d_ws;
    short* bTf  = aTf + 12288 * 128;
    short* wbTf = bTf + 12288 * 128;
    short* wcT  = wbTf + 128 * 1024;

    k_transpose_wout<<<dim3(16, 2), 256, 0, stream>>>(w_out, wbTf);
    k_pack_w12<<<64, 256, 0, stream>>>(w1, w2, wcT);
    k_ln_proj<<<768, 256, 0, stream>>>(M, ln_g, ln_b, b1, b2, wcT, aTf, bTf);
    k_opm<<<256, 512, 0, stream>>>(aTf, bTf, wbTf, b_out, out);
}